// Round 1
// baseline (142.320 us; speedup 1.0000x reference)
//
#include <hip/hip_runtime.h>
#include <math.h>

namespace {
constexpr int kB = 4;
constexpr int kS = 4096;
constexpr int kH = 4096;
constexpr int kE = 16;
constexpr int kTokens = kB * kS;            // 16384
constexpr int kT = 4;                       // tokens per wave (reg-blocking for W reuse)
constexpr int kWavesPerBlock = 4;
constexpr int kBlockThreads = 64 * kWavesPerBlock;      // 256
constexpr int kTokensPerBlock = kT * kWavesPerBlock;    // 16
constexpr int kGrid = kTokens / kTokensPerBlock;        // 1024
}  // namespace

// Main kernel: gate GEMM (f32 vector, reg-blocked) + softmax + top-2 + aux partials.
__global__ __launch_bounds__(kBlockThreads) void router_main(
    const float* __restrict__ x, const float* __restrict__ W,
    float* __restrict__ out_probs,   // [kTokens][2]
    float* __restrict__ out_idx,     // [kTokens][2] (indices stored as float)
    float* __restrict__ gsum) {      // [2*kE]: counts[16], probsum[16]
  __shared__ float s_cnt[kE];
  __shared__ float s_psum[kE];
  const int tid = threadIdx.x;
  if (tid < kE) { s_cnt[tid] = 0.f; s_psum[tid] = 0.f; }
  __syncthreads();

  const int wave = tid >> 6;
  const int lane = tid & 63;
  const int tok0 = (blockIdx.x * kWavesPerBlock + wave) * kT;

  float acc[kT][kE];
#pragma unroll
  for (int t = 0; t < kT; ++t)
#pragma unroll
    for (int e = 0; e < kE; ++e) acc[t][e] = 0.f;

  const float* xrow = x + (size_t)tok0 * kH;

  // 16 j-iters: each iter the wave reads 256 contiguous floats per token
  // (lane*4 offsets -> perfectly coalesced float4) and the matching 256-float
  // slice of each of the 16 expert rows of W (L2-resident, reused 4x via kT).
#pragma unroll 2
  for (int j = 0; j < kH / 256; ++j) {
    const int off = j * 256 + lane * 4;
    float4 xv[kT];
#pragma unroll
    for (int t = 0; t < kT; ++t)
      xv[t] = *reinterpret_cast<const float4*>(xrow + (size_t)t * kH + off);
#pragma unroll
    for (int e = 0; e < kE; ++e) {
      const float4 wv = *reinterpret_cast<const float4*>(W + (size_t)e * kH + off);
#pragma unroll
      for (int t = 0; t < kT; ++t) {
        acc[t][e] = fmaf(xv[t].x, wv.x, acc[t][e]);
        acc[t][e] = fmaf(xv[t].y, wv.y, acc[t][e]);
        acc[t][e] = fmaf(xv[t].z, wv.z, acc[t][e]);
        acc[t][e] = fmaf(xv[t].w, wv.w, acc[t][e]);
      }
    }
  }

  // Butterfly reduction across the 64-lane wave: every lane ends with full sums.
#pragma unroll
  for (int off = 1; off < 64; off <<= 1) {
#pragma unroll
    for (int t = 0; t < kT; ++t)
#pragma unroll
      for (int e = 0; e < kE; ++e)
        acc[t][e] += __shfl_xor(acc[t][e], off, 64);
  }

  // Lanes 0..kT-1 each finish one token.
  if (lane < kT) {
    const int tok = tok0 + lane;
    float l[kE];
#pragma unroll
    for (int e = 0; e < kE; ++e) l[e] = acc[lane][e];

    float m = l[0];
#pragma unroll
    for (int e = 1; e < kE; ++e) m = fmaxf(m, l[e]);
    float p[kE];
    float s = 0.f;
#pragma unroll
    for (int e = 0; e < kE; ++e) { p[e] = __expf(l[e] - m); s += p[e]; }
    const float inv = 1.f / s;
#pragma unroll
    for (int e = 0; e < kE; ++e) p[e] *= inv;

    // top-2 on probs (matches reference: top_k AFTER softmax; ties -> lowest index)
    int i1 = 0;
    float v1 = p[0];
#pragma unroll
    for (int e = 1; e < kE; ++e)
      if (p[e] > v1) { v1 = p[e]; i1 = e; }
    int i2 = (i1 == 0) ? 1 : 0;
    float v2 = p[i2];
#pragma unroll
    for (int e = 0; e < kE; ++e) {
      if (e == i1) continue;
      if (p[e] > v2) { v2 = p[e]; i2 = e; }
    }

    const float ns = 1.f / (v1 + v2);
    out_probs[tok * 2 + 0] = v1 * ns;
    out_probs[tok * 2 + 1] = v2 * ns;
    out_idx[tok * 2 + 0] = (float)i1;
    out_idx[tok * 2 + 1] = (float)i2;

#pragma unroll
    for (int e = 0; e < kE; ++e) atomicAdd(&s_psum[e], p[e]);
    atomicAdd(&s_cnt[i1], 1.f);
    atomicAdd(&s_cnt[i2], 1.f);
  }
  __syncthreads();
  if (tid < kE) {
    atomicAdd(&gsum[tid], s_cnt[tid]);          // counts (exact small ints in f32)
    atomicAdd(&gsum[kE + tid], s_psum[tid]);    // prob sums
  }
}

// aux_loss = E * sum_e (count_e / B) * (probsum_e / (B*S))
__global__ void aux_finish(const float* __restrict__ gsum, float* __restrict__ out_aux) {
  if (threadIdx.x == 0 && blockIdx.x == 0) {
    double acc = 0.0;
    for (int e = 0; e < kE; ++e)
      acc += (double)gsum[e] * (double)gsum[kE + e];
    out_aux[0] = (float)(acc * (double)kE / ((double)kB * (double)kB * (double)kS));
  }
}

extern "C" void kernel_launch(void* const* d_in, const int* in_sizes, int n_in,
                              void* d_out, int out_size, void* d_ws, size_t ws_size,
                              hipStream_t stream) {
  const float* x = (const float*)d_in[0];   // [B,S,H] f32
  const float* W = (const float*)d_in[1];   // [E,H]   f32
  float* out = (float*)d_out;               // [32768 probs][32768 idx][1 aux]
  float* gsum = (float*)d_ws;

  hipMemsetAsync(d_ws, 0, 2 * kE * sizeof(float), stream);
  router_main<<<kGrid, kBlockThreads, 0, stream>>>(
      x, W, out, out + 2 * kTokens, gsum);
  aux_finish<<<1, 64, 0, stream>>>(gsum, out + 4 * kTokens);
}